// Round 2
// baseline (205.818 us; speedup 1.0000x reference)
//
#include <hip/hip_runtime.h>

// LinearAttention: B=2, L=2048, D=1024, H=16, d=64.
// cvt_all(fp32->bf16) ; QKV GEMM (bf16 MFMA) ; kv_local ; kv_prefix (parallel) ;
// attn_chunk (P=tril(QK^T), Y=PV+QS) ; out GEMM (BM=64 for 2 blocks/CU).
// LDS layouts: "panelized column-major" (slot = chunk*16 + row within 16-row
// panels) so glds16's lane-contiguous scatter yields 2-way-max bank aliasing
// on ds_read_b128 (2-way is free, m136). Manually-staged tiles use +8 padding.

#define DEV __device__ __forceinline__

typedef __attribute__((ext_vector_type(8))) short bf16x8;
typedef __attribute__((ext_vector_type(4))) float f32x4;

DEV ushort f2bf(float f) {
  union { float f; unsigned u; } v; v.f = f;
  unsigned r = v.u + 0x7fffu + ((v.u >> 16) & 1u);
  return (ushort)(r >> 16);
}
DEV float bf2f(unsigned b) {
  union { unsigned u; float f; } v; v.u = (b & 0xffffu) << 16;
  return v.f;
}
DEV void glds16(const ushort* g, ushort* l) {
  __builtin_amdgcn_global_load_lds(
      (const __attribute__((address_space(1))) unsigned int*)g,
      (__attribute__((address_space(3))) unsigned int*)l, 16, 0, 0);
}

// One launch converts x, Wqkv_w, out_w to bf16 (saves 2 dispatch overheads).
__global__ __launch_bounds__(256) void cvt_all(const float* __restrict__ x,
                                               const float* __restrict__ Ww,
                                               const float* __restrict__ Ow,
                                               ushort* __restrict__ xb,
                                               ushort* __restrict__ wqkvb,
                                               ushort* __restrict__ outwb) {
  int i = blockIdx.x * 256 + threadIdx.x;  // 2097152 float4s total
  const float* src; ushort* dst; int off;
  if (i < 1048576)      { src = x;  dst = xb;    off = i; }
  else if (i < 1835008) { src = Ww; dst = wqkvb; off = i - 1048576; }
  else                  { src = Ow; dst = outwb; off = i - 1835008; }
  float4 v = ((const float4*)src)[off];
  ushort4 o;
  o.x = f2bf(v.x); o.y = f2bf(v.y); o.z = f2bf(v.z); o.w = f2bf(v.w);
  ((ushort4*)dst)[off] = o;
}

// C = A[M,K] * Bw[N,K]^T + bias ; 128x128x32 tiles, panelized col-major LDS.
template <bool OUT_BF16, bool KSCALE>
__global__ __launch_bounds__(256) void gemm_bt(const ushort* __restrict__ A,
                                               const ushort* __restrict__ Bw,
                                               const float* __restrict__ bias,
                                               void* __restrict__ Cout,
                                               int M, int N, int K) {
  __shared__ ushort As[128 * 32];  // 8 panels x 512 ushorts
  __shared__ ushort Bs[128 * 32];
  const int t = threadIdx.x;
  const int wid = t >> 6, lane = t & 63;
  const int quad = lane >> 4, l16 = lane & 15;
  const int bm = blockIdx.y * 128, bn = blockIdx.x * 128;
  const int wm = (wid >> 1) * 64, wn = (wid & 1) * 64;

  f32x4 acc[4][4];
  const f32x4 z = {0.f, 0.f, 0.f, 0.f};
#pragma unroll
  for (int i = 0; i < 4; ++i)
#pragma unroll
    for (int j = 0; j < 4; ++j) acc[i][j] = z;

  // lane fetches (row = wid*16 + (lane&15), k-chunk = lane>>4) -> LDS slot = lane
  const ushort* ag = A + (size_t)(bm + wid * 16 + (lane & 15)) * K + ((lane >> 4) * 8);
  const ushort* bg = Bw + (size_t)(bn + wid * 16 + (lane & 15)) * K + ((lane >> 4) * 8);
  ushort* asl = As + wid * 512;
  ushort* bsl = Bs + wid * 512;
  const size_t rowskip = (size_t)64 * K;

  for (int k0 = 0; k0 < K; k0 += 32) {
    glds16(ag + k0, asl);
    glds16(ag + k0 + rowskip, asl + 2048);
    glds16(bg + k0, bsl);
    glds16(bg + k0 + rowskip, bsl + 2048);
    __syncthreads();
    bf16x8 af[4], bf[4];
#pragma unroll
    for (int i = 0; i < 4; ++i) {
      af[i] = *(const bf16x8*)(As + ((wm >> 4) + i) * 512 + quad * 128 + l16 * 8);
      bf[i] = *(const bf16x8*)(Bs + ((wn >> 4) + i) * 512 + quad * 128 + l16 * 8);
    }
#pragma unroll
    for (int i = 0; i < 4; ++i)
#pragma unroll
      for (int j = 0; j < 4; ++j)
        acc[i][j] = __builtin_amdgcn_mfma_f32_16x16x32_bf16(af[i], bf[j], acc[i][j], 0, 0, 0);
    __syncthreads();
  }

#pragma unroll
  for (int i = 0; i < 4; ++i)
#pragma unroll
    for (int j = 0; j < 4; ++j) {
      const int col = bn + wn + j * 16 + l16;
      const float bv = bias[col];
      float sc = 1.f;
      if (KSCALE) sc = ((col >> 10) == 1) ? 0.125f : 1.f;
#pragma unroll
      for (int r = 0; r < 4; ++r) {
        const int row = bm + wm + i * 16 + quad * 4 + r;
        const float v = (acc[i][j][r] + bv) * sc;
        if (OUT_BF16)
          ((ushort*)Cout)[(size_t)row * N + col] = f2bf(v);
        else
          ((float*)Cout)[(size_t)row * N + col] = v;
      }
    }
}

// Out projection: BM=64, BN=128 -> 512 blocks (2/CU instead of 1/CU).
__global__ __launch_bounds__(256) void gemm_out64(const ushort* __restrict__ A,
                                                  const ushort* __restrict__ Bw,
                                                  const float* __restrict__ bias,
                                                  float* __restrict__ C,
                                                  int M, int N, int K) {
  __shared__ ushort As[64 * 32];   // 4 panels
  __shared__ ushort Bs[128 * 32];  // 8 panels
  const int t = threadIdx.x;
  const int wid = t >> 6, lane = t & 63;
  const int quad = lane >> 4, l16 = lane & 15;
  const int bm = blockIdx.y * 64, bn = blockIdx.x * 128;
  const int wn = wid * 32;

  f32x4 acc[4][2];
  const f32x4 z = {0.f, 0.f, 0.f, 0.f};
#pragma unroll
  for (int i = 0; i < 4; ++i) { acc[i][0] = z; acc[i][1] = z; }

  const ushort* ag = A + (size_t)(bm + wid * 16 + (lane & 15)) * K + ((lane >> 4) * 8);
  const ushort* bg = Bw + (size_t)(bn + wid * 16 + (lane & 15)) * K + ((lane >> 4) * 8);
  ushort* asl = As + wid * 512;
  ushort* bsl = Bs + wid * 512;
  const size_t rowskip = (size_t)64 * K;

  for (int k0 = 0; k0 < K; k0 += 32) {
    glds16(ag + k0, asl);
    glds16(bg + k0, bsl);
    glds16(bg + k0 + rowskip, bsl + 2048);
    __syncthreads();
    bf16x8 af[4], bf[2];
#pragma unroll
    for (int i = 0; i < 4; ++i)
      af[i] = *(const bf16x8*)(As + i * 512 + quad * 128 + l16 * 8);
#pragma unroll
    for (int j = 0; j < 2; ++j)
      bf[j] = *(const bf16x8*)(Bs + (wid * 2 + j) * 512 + quad * 128 + l16 * 8);
#pragma unroll
    for (int i = 0; i < 4; ++i)
#pragma unroll
      for (int j = 0; j < 2; ++j)
        acc[i][j] = __builtin_amdgcn_mfma_f32_16x16x32_bf16(af[i], bf[j], acc[i][j], 0, 0, 0);
    __syncthreads();
  }

#pragma unroll
  for (int i = 0; i < 4; ++i)
#pragma unroll
    for (int j = 0; j < 2; ++j) {
      const int col = bn + wn + j * 16 + l16;
      const float bv = bias[col];
#pragma unroll
      for (int r = 0; r < 4; ++r) {
        const int row = bm + i * 16 + quad * 4 + r;
        C[(size_t)row * N + col] = acc[i][j][r] + bv;
      }
    }
}

// Per-(bh,chunk) local KV outer-product sums: mlocT[bh][c][e][f] = sum_s v[s][e]*k[s][f]
__global__ __launch_bounds__(256) void kv_local(const ushort* __restrict__ qkv,
                                                float* __restrict__ mlocT) {
  const int c = blockIdx.x, bh = blockIdx.y;
  const int b = bh >> 4, hd = bh & 15;
  const int t = threadIdx.x;
  __shared__ float kk[32 * 65];
  __shared__ float vv[32 * 65];
  float s[16];
#pragma unroll
  for (int j = 0; j < 16; ++j) s[j] = 0.f;
  const int e = t >> 2, fb = (t & 3) * 16;
  const int step = t >> 3, el = (t & 7) * 8;
  for (int sb = 0; sb < 4; ++sb) {
    const ushort* kg = qkv + (size_t)(b * 2048 + c * 128 + sb * 32 + step) * 3072 + 1024 + hd * 64 + el;
    uint4 kr = *(const uint4*)kg;
    uint4 vr = *(const uint4*)(kg + 1024);
    float* kd = kk + step * 65 + el;
    float* vd = vv + step * 65 + el;
    kd[0] = bf2f(kr.x); kd[1] = bf2f(kr.x >> 16);
    kd[2] = bf2f(kr.y); kd[3] = bf2f(kr.y >> 16);
    kd[4] = bf2f(kr.z); kd[5] = bf2f(kr.z >> 16);
    kd[6] = bf2f(kr.w); kd[7] = bf2f(kr.w >> 16);
    vd[0] = bf2f(vr.x); vd[1] = bf2f(vr.x >> 16);
    vd[2] = bf2f(vr.y); vd[3] = bf2f(vr.y >> 16);
    vd[4] = bf2f(vr.z); vd[5] = bf2f(vr.z >> 16);
    vd[6] = bf2f(vr.w); vd[7] = bf2f(vr.w >> 16);
    __syncthreads();
    for (int l = 0; l < 32; ++l) {
      const float ve = vv[l * 65 + e];
      const float* krow = kk + l * 65 + fb;
#pragma unroll
      for (int j = 0; j < 16; ++j) s[j] += ve * krow[j];
    }
    __syncthreads();
  }
  float* out = mlocT + ((size_t)bh * 16 + c) * 4096 + e * 64 + fb;
#pragma unroll
  for (int j = 0; j < 16; ++j) out[j] = s[j];
}

// Exclusive prefix over chunks — parallel over the 4096 independent entries.
// grid (16 slices, 32 bh); coalesced 1KB reads per block per chunk.
__global__ __launch_bounds__(256) void kv_prefix(const float* __restrict__ mlocT,
                                                 ushort* __restrict__ statesT) {
  const int slice = blockIdx.x, bh = blockIdx.y;
  const int eidx = slice * 256 + threadIdx.x;
  float run = 0.f;
  for (int c = 0; c < 16; ++c) {
    const size_t idx = ((size_t)bh * 16 + c) * 4096 + eidx;
    statesT[idx] = f2bf(run);
    run += mlocT[idx];
  }
}

// Per-(bh,chunk): P = tril(Q K^T) ; Y = P V + Q S_prefix
__global__ __launch_bounds__(256) void attn_chunk(const ushort* __restrict__ qkv,
                                                  const ushort* __restrict__ statesT,
                                                  ushort* __restrict__ yb) {
  const int c = blockIdx.x, bh = blockIdx.y;
  const int b = bh >> 4, hd = bh & 15;
  const int l0 = c * 128;
  const int t = threadIdx.x;
  const int wid = t >> 6, lane = t & 63;
  const int quad = lane >> 4, l16 = lane & 15;

  __shared__ ushort P[16384];  // 8 row-panels x (16 chunks x 16 rows) col-major
  __shared__ ushort U[16384];
  ushort* Qs = U;              // 8 panels x 1024 (col-major within panel)
  ushort* Ks = U + 8192;
  ushort* vT = U;              // phase2: [e:64][s:128] padded rows of 136
  ushort* sT = U + 8704;       // phase2: [e:64][f:64]  padded rows of 72

  {  // zero P
    uint4 zz; zz.x = zz.y = zz.z = zz.w = 0u;
    uint4* p4 = (uint4*)P;
#pragma unroll
    for (int i = 0; i < 8; ++i) p4[i * 256 + t] = zz;
  }
  {  // stage Q,K: panelized col-major; lane -> (row=lane&15, chunk=lane>>4)
    const ushort* qbase = qkv + (size_t)(b * 2048 + l0 + (lane & 15)) * 3072 + hd * 64 + ((lane >> 4) * 8);
#pragma unroll
    for (int pp = 0; pp < 2; ++pp) {
      const int p = wid * 2 + pp;
      const ushort* qg = qbase + (size_t)(p * 16) * 3072;
      glds16(qg, Qs + p * 1024);              // cols 0..31
      glds16(qg + 32, Qs + p * 1024 + 512);   // cols 32..63
      glds16(qg + 1024, Ks + p * 1024);
      glds16(qg + 1024 + 32, Ks + p * 1024 + 512);
    }
  }
  __syncthreads();

  bf16x8 qf[2][2];
#pragma unroll
  for (int i = 0; i < 2; ++i)
#pragma unroll
    for (int kc = 0; kc < 2; ++kc)
      qf[i][kc] = *(const bf16x8*)(Qs + (wid * 2 + i) * 1024 + (kc * 4 + quad) * 128 + l16 * 8);

  const f32x4 z4 = {0.f, 0.f, 0.f, 0.f};
  f32x4 pacc[2][8];
#pragma unroll
  for (int i = 0; i < 2; ++i)
#pragma unroll
    for (int j = 0; j < 8; ++j) pacc[i][j] = z4;

#pragma unroll
  for (int i = 0; i < 2; ++i) {
    const int rt = wid * 2 + i;
#pragma unroll
    for (int tj = 0; tj < 8; ++tj) {
      if (tj <= rt) {
#pragma unroll
        for (int kc = 0; kc < 2; ++kc) {
          bf16x8 kfr = *(const bf16x8*)(Ks + tj * 1024 + (kc * 4 + quad) * 128 + l16 * 8);
          pacc[i][tj] = __builtin_amdgcn_mfma_f32_16x16x32_bf16(qf[i][kc], kfr, pacc[i][tj], 0, 0, 0);
        }
      }
    }
  }
  __syncthreads();

  // write masked P into panelized col-major layout
#pragma unroll
  for (int i = 0; i < 2; ++i) {
    const int rt = wid * 2 + i;
#pragma unroll
    for (int tj = 0; tj < 8; ++tj) {
      if (tj <= rt) {
#pragma unroll
        for (int r = 0; r < 4; ++r) {
          const int rowin = quad * 4 + r;
          const int scol = tj * 16 + l16;
          const float v = (scol <= rt * 16 + rowin) ? pacc[i][tj][r] : 0.f;
          P[rt * 2048 + (scol >> 3) * 128 + rowin * 8 + (scol & 7)] = f2bf(v);
        }
      }
    }
  }
  {  // stage V transposed: vT[e][s], padded stride 136
    const int sstep = t >> 1, eb = (t & 1) * 32;
    const ushort* vg = qkv + (size_t)(b * 2048 + l0 + sstep) * 3072 + 2048 + hd * 64 + eb;
    ushort tmp[32];
    *(uint4*)(tmp + 0)  = *(const uint4*)(vg + 0);
    *(uint4*)(tmp + 8)  = *(const uint4*)(vg + 8);
    *(uint4*)(tmp + 16) = *(const uint4*)(vg + 16);
    *(uint4*)(tmp + 24) = *(const uint4*)(vg + 24);
#pragma unroll
    for (int j = 0; j < 32; ++j) vT[(eb + j) * 136 + sstep] = tmp[j];
  }
  {  // stage S: [e][f] padded stride 72
    const ushort* sg = statesT + ((size_t)bh * 16 + c) * 4096;
#pragma unroll
    for (int s = t; s < 512; s += 256) {
      uint4 d = *(const uint4*)(sg + s * 8);
      *(uint4*)(sT + (s >> 3) * 72 + (s & 7) * 8) = d;
    }
  }
  __syncthreads();

  f32x4 yacc[2][4];
#pragma unroll
  for (int i = 0; i < 2; ++i)
#pragma unroll
    for (int j = 0; j < 4; ++j) yacc[i][j] = z4;

#pragma unroll
  for (int i = 0; i < 2; ++i) {
    const int rt = wid * 2 + i;
    const int kcmax = rt >> 1;
#pragma unroll
    for (int kc = 0; kc < 4; ++kc) {
      if (kc <= kcmax) {
        bf16x8 pf = *(const bf16x8*)(P + rt * 2048 + (kc * 4 + quad) * 128 + l16 * 8);
#pragma unroll
        for (int ct = 0; ct < 4; ++ct) {
          bf16x8 vf = *(const bf16x8*)(vT + (ct * 16 + l16) * 136 + kc * 32 + quad * 8);
          yacc[i][ct] = __builtin_amdgcn_mfma_f32_16x16x32_bf16(pf, vf, yacc[i][ct], 0, 0, 0);
        }
      }
    }
#pragma unroll
    for (int kc = 0; kc < 2; ++kc) {
#pragma unroll
      for (int ct = 0; ct < 4; ++ct) {
        bf16x8 sf = *(const bf16x8*)(sT + (ct * 16 + l16) * 72 + kc * 32 + quad * 8);
        yacc[i][ct] = __builtin_amdgcn_mfma_f32_16x16x32_bf16(qf[i][kc], sf, yacc[i][ct], 0, 0, 0);
      }
    }
  }

#pragma unroll
  for (int i = 0; i < 2; ++i) {
    const int rt = wid * 2 + i;
#pragma unroll
    for (int ct = 0; ct < 4; ++ct) {
#pragma unroll
      for (int r = 0; r < 4; ++r) {
        const int row = rt * 16 + quad * 4 + r;
        const int e = ct * 16 + l16;
        yb[(size_t)(b * 2048 + l0 + row) * 1024 + hd * 64 + e] = f2bf(yacc[i][ct][r]);
      }
    }
  }
}

extern "C" void kernel_launch(void* const* d_in, const int* in_sizes, int n_in,
                              void* d_out, int out_size, void* d_ws, size_t ws_size,
                              hipStream_t stream) {
  const float* x  = (const float*)d_in[0];
  const float* Ww = (const float*)d_in[1];
  const float* Wb = (const float*)d_in[2];
  const float* Ow = (const float*)d_in[3];
  const float* Ob = (const float*)d_in[4];
  float* out = (float*)d_out;

  char* ws = (char*)d_ws;
  ushort* xb      = (ushort*)(ws);
  ushort* wqkvb   = (ushort*)(ws + (size_t)8  * 1024 * 1024);
  ushort* outwb   = (ushort*)(ws + (size_t)14 * 1024 * 1024);
  ushort* qkvb    = (ushort*)(ws + (size_t)16 * 1024 * 1024);
  float*  mlocT   = (float*) (ws + (size_t)40 * 1024 * 1024);
  ushort* statesT = (ushort*)(ws + (size_t)48 * 1024 * 1024);
  ushort* yb      = (ushort*)(ws + (size_t)52 * 1024 * 1024);

  cvt_all<<<8192, 256, 0, stream>>>(x, Ww, Ow, xb, wqkvb, outwb);
  gemm_bt<true, true><<<dim3(24, 32), 256, 0, stream>>>(xb, wqkvb, Wb, (void*)qkvb, 4096, 3072, 1024);
  kv_local<<<dim3(16, 32), 256, 0, stream>>>(qkvb, mlocT);
  kv_prefix<<<dim3(16, 32), 256, 0, stream>>>(mlocT, statesT);
  attn_chunk<<<dim3(16, 32), 256, 0, stream>>>(qkvb, statesT, yb);
  gemm_out64<<<dim3(8, 64), 256, 0, stream>>>(yb, outwb, Ob, out, 4096, 1024, 1024);
}

// Round 3
// 190.067 us; speedup vs baseline: 1.0829x; 1.0829x over previous
//
#include <hip/hip_runtime.h>

// LinearAttention: B=2, L=2048, D=1024, H=16, d=64.
// cvt_all ; QKV GEMM ; kv_local ; attn_chunk (prefix folded in) ; out GEMM.
// Staging: round-1 lane-contiguous global footprint + XOR chunk swizzle
// sigma(c) = c ^ ((c>>3)&7) so ds_read_b128 fragments hit each bank-group
// exactly twice (2-way = free, m136) while each 4-lane global run still
// covers one whole 64B row segment (round-2 lesson: global lane scatter
// costs ~30%, far more than 8-way LDS conflicts).

#define DEV __device__ __forceinline__

typedef __attribute__((ext_vector_type(8))) short bf16x8;
typedef __attribute__((ext_vector_type(4))) float f32x4;

DEV ushort f2bf(float f) {
  union { float f; unsigned u; } v; v.f = f;
  unsigned r = v.u + 0x7fffu + ((v.u >> 16) & 1u);
  return (ushort)(r >> 16);
}
DEV float bf2f(unsigned b) {
  union { unsigned u; float f; } v; v.u = (b & 0xffffu) << 16;
  return v.f;
}
DEV void glds16(const ushort* g, ushort* l) {
  __builtin_amdgcn_global_load_lds(
      (const __attribute__((address_space(1))) unsigned int*)g,
      (__attribute__((address_space(3))) unsigned int*)l, 16, 0, 0);
}

__global__ __launch_bounds__(256) void cvt_all(const float* __restrict__ x,
                                               const float* __restrict__ Ww,
                                               const float* __restrict__ Ow,
                                               ushort* __restrict__ xb,
                                               ushort* __restrict__ wqkvb,
                                               ushort* __restrict__ outwb) {
  int i = blockIdx.x * 256 + threadIdx.x;
  const float* src; ushort* dst; int off;
  if (i < 1048576)      { src = x;  dst = xb;    off = i; }
  else if (i < 1835008) { src = Ww; dst = wqkvb; off = i - 1048576; }
  else                  { src = Ow; dst = outwb; off = i - 1835008; }
  float4 v = ((const float4*)src)[off];
  ushort4 o;
  o.x = f2bf(v.x); o.y = f2bf(v.y); o.z = f2bf(v.z); o.w = f2bf(v.w);
  ((ushort4*)dst)[off] = o;
}

// C = A[M,K] * Bw[N,K]^T + bias ; 128x128x32 tiles, XOR-swizzled LDS slots.
template <bool OUT_BF16, bool KSCALE>
__global__ __launch_bounds__(256) void gemm_bt(const ushort* __restrict__ A,
                                               const ushort* __restrict__ Bw,
                                               const float* __restrict__ bias,
                                               void* __restrict__ Cout,
                                               int M, int N, int K) {
  __shared__ ushort As[128 * 32];  // 8 panels x 512 ushorts (16 rows x 64B)
  __shared__ ushort Bs[128 * 32];
  const int t = threadIdx.x;
  const int wid = t >> 6, lane = t & 63;
  const int quad = lane >> 4, l16 = lane & 15;
  const int bm = blockIdx.y * 128, bn = blockIdx.x * 128;
  const int wm = (wid >> 1) * 64, wn = (wid & 1) * 64;

  f32x4 acc[4][4];
  const f32x4 z = {0.f, 0.f, 0.f, 0.f};
#pragma unroll
  for (int i = 0; i < 4; ++i)
#pragma unroll
    for (int j = 0; j < 4; ++j) acc[i][j] = z;

  // lane L stages chunk sigma(L): row sl>>2, 16B-col sl&3 (footprint = round-1)
  const int sl = lane ^ ((lane >> 3) & 7);
  const ushort* ag = A + (size_t)(bm + wid * 16 + (sl >> 2)) * K + ((sl & 3) * 8);
  const ushort* bg = Bw + (size_t)(bn + wid * 16 + (sl >> 2)) * K + ((sl & 3) * 8);
  ushort* asl = As + wid * 512;
  ushort* bsl = Bs + wid * 512;
  const size_t rowskip = (size_t)64 * K;

  // read-side swizzled slot for fragment (row l16, chunk quad)
  const int rslot = ((l16 * 4 + quad) ^ (l16 >> 1)) * 8;

  for (int k0 = 0; k0 < K; k0 += 32) {
    glds16(ag + k0, asl);
    glds16(ag + k0 + rowskip, asl + 2048);
    glds16(bg + k0, bsl);
    glds16(bg + k0 + rowskip, bsl + 2048);
    __syncthreads();
    bf16x8 af[4], bf[4];
#pragma unroll
    for (int i = 0; i < 4; ++i) {
      af[i] = *(const bf16x8*)(As + ((wm >> 4) + i) * 512 + rslot);
      bf[i] = *(const bf16x8*)(Bs + ((wn >> 4) + i) * 512 + rslot);
    }
#pragma unroll
    for (int i = 0; i < 4; ++i)
#pragma unroll
      for (int j = 0; j < 4; ++j)
        acc[i][j] = __builtin_amdgcn_mfma_f32_16x16x32_bf16(af[i], bf[j], acc[i][j], 0, 0, 0);
    __syncthreads();
  }

#pragma unroll
  for (int i = 0; i < 4; ++i)
#pragma unroll
    for (int j = 0; j < 4; ++j) {
      const int col = bn + wn + j * 16 + l16;
      const float bv = bias[col];
      float sc = 1.f;
      if (KSCALE) sc = ((col >> 10) == 1) ? 0.125f : 1.f;
#pragma unroll
      for (int r = 0; r < 4; ++r) {
        const int row = bm + wm + i * 16 + quad * 4 + r;
        const float v = (acc[i][j][r] + bv) * sc;
        if (OUT_BF16)
          ((ushort*)Cout)[(size_t)row * N + col] = f2bf(v);
        else
          ((float*)Cout)[(size_t)row * N + col] = v;
      }
    }
}

// Out projection: BM=64, BN=128 -> 512 blocks (2/CU).
__global__ __launch_bounds__(256) void gemm_out64(const ushort* __restrict__ A,
                                                  const ushort* __restrict__ Bw,
                                                  const float* __restrict__ bias,
                                                  float* __restrict__ C,
                                                  int M, int N, int K) {
  __shared__ ushort As[64 * 32];   // 4 panels
  __shared__ ushort Bs[128 * 32];  // 8 panels
  const int t = threadIdx.x;
  const int wid = t >> 6, lane = t & 63;
  const int quad = lane >> 4, l16 = lane & 15;
  const int bm = blockIdx.y * 64, bn = blockIdx.x * 128;
  const int wn = wid * 32;

  f32x4 acc[4][2];
  const f32x4 z = {0.f, 0.f, 0.f, 0.f};
#pragma unroll
  for (int i = 0; i < 4; ++i) { acc[i][0] = z; acc[i][1] = z; }

  const int sl = lane ^ ((lane >> 3) & 7);
  const ushort* ag = A + (size_t)(bm + wid * 16 + (sl >> 2)) * K + ((sl & 3) * 8);
  const ushort* bg = Bw + (size_t)(bn + wid * 16 + (sl >> 2)) * K + ((sl & 3) * 8);
  ushort* asl = As + wid * 512;
  ushort* bsl = Bs + wid * 512;
  const size_t rowskip = (size_t)64 * K;
  const int rslot = ((l16 * 4 + quad) ^ (l16 >> 1)) * 8;

  for (int k0 = 0; k0 < K; k0 += 32) {
    glds16(ag + k0, asl);
    glds16(bg + k0, bsl);
    glds16(bg + k0 + rowskip, bsl + 2048);
    __syncthreads();
    bf16x8 af[4], bf[2];
#pragma unroll
    for (int i = 0; i < 4; ++i)
      af[i] = *(const bf16x8*)(As + i * 512 + rslot);
#pragma unroll
    for (int j = 0; j < 2; ++j)
      bf[j] = *(const bf16x8*)(Bs + (wid * 2 + j) * 512 + rslot);
#pragma unroll
    for (int i = 0; i < 4; ++i)
#pragma unroll
      for (int j = 0; j < 2; ++j)
        acc[i][j] = __builtin_amdgcn_mfma_f32_16x16x32_bf16(af[i], bf[j], acc[i][j], 0, 0, 0);
    __syncthreads();
  }

#pragma unroll
  for (int i = 0; i < 4; ++i)
#pragma unroll
    for (int j = 0; j < 2; ++j) {
      const int col = bn + wn + j * 16 + l16;
      const float bv = bias[col];
#pragma unroll
      for (int r = 0; r < 4; ++r) {
        const int row = bm + i * 16 + quad * 4 + r;
        C[(size_t)row * N + col] = acc[i][j][r] + bv;
      }
    }
}

// Per-(bh,chunk) local KV sums: mlocT[bh][c][e][f] = sum_s v[s][e]*k[s][f]
__global__ __launch_bounds__(256) void kv_local(const ushort* __restrict__ qkv,
                                                float* __restrict__ mlocT) {
  const int c = blockIdx.x, bh = blockIdx.y;
  const int b = bh >> 4, hd = bh & 15;
  const int t = threadIdx.x;
  __shared__ float kk[32 * 65];
  __shared__ float vv[32 * 65];
  float s[16];
#pragma unroll
  for (int j = 0; j < 16; ++j) s[j] = 0.f;
  const int e = t >> 2, fb = (t & 3) * 16;
  const int step = t >> 3, el = (t & 7) * 8;
  for (int sb = 0; sb < 4; ++sb) {
    const ushort* kg = qkv + (size_t)(b * 2048 + c * 128 + sb * 32 + step) * 3072 + 1024 + hd * 64 + el;
    uint4 kr = *(const uint4*)kg;
    uint4 vr = *(const uint4*)(kg + 1024);
    float* kd = kk + step * 65 + el;
    float* vd = vv + step * 65 + el;
    kd[0] = bf2f(kr.x); kd[1] = bf2f(kr.x >> 16);
    kd[2] = bf2f(kr.y); kd[3] = bf2f(kr.y >> 16);
    kd[4] = bf2f(kr.z); kd[5] = bf2f(kr.z >> 16);
    kd[6] = bf2f(kr.w); kd[7] = bf2f(kr.w >> 16);
    vd[0] = bf2f(vr.x); vd[1] = bf2f(vr.x >> 16);
    vd[2] = bf2f(vr.y); vd[3] = bf2f(vr.y >> 16);
    vd[4] = bf2f(vr.z); vd[5] = bf2f(vr.z >> 16);
    vd[6] = bf2f(vr.w); vd[7] = bf2f(vr.w >> 16);
    __syncthreads();
    for (int l = 0; l < 32; ++l) {
      const float ve = vv[l * 65 + e];
      const float* krow = kk + l * 65 + fb;
#pragma unroll
      for (int j = 0; j < 16; ++j) s[j] += ve * krow[j];
    }
    __syncthreads();
  }
  float* out = mlocT + ((size_t)bh * 16 + c) * 4096 + e * 64 + fb;
#pragma unroll
  for (int j = 0; j < 16; ++j) out[j] = s[j];
}

// Per-(bh,chunk): P = tril(Q K^T) ; Y = P V + Q S_prefix.
// Prefix state computed in-kernel from mlocT (chunks < c), overlapped w/ MFMA.
__global__ __launch_bounds__(256) void attn_chunk(const ushort* __restrict__ qkv,
                                                  const float* __restrict__ mlocT,
                                                  ushort* __restrict__ yb) {
  const int c = blockIdx.x, bh = blockIdx.y;
  const int b = bh >> 4, hd = bh & 15;
  const int l0 = c * 128;
  const int t = threadIdx.x;
  const int wid = t >> 6, lane = t & 63;
  const int quad = lane >> 4, l16 = lane & 15;

  __shared__ ushort P[16384];  // [row][16 chunks of 16B] XOR-swizzled by row&7
  __shared__ ushort U[16384];
  ushort* Qs = U;              // [row:128][64] rows XOR-swizzled (chunk^row&7)
  ushort* Ks = U + 8192;
  ushort* vT = U;              // phase2: [e:64][s:128] stride 136
  ushort* sT = U + 8704;       // phase2: [e:64][f:64]  stride 72

  {  // zero P
    uint4 zz; zz.x = zz.y = zz.z = zz.w = 0u;
    uint4* p4 = (uint4*)P;
#pragma unroll
    for (int i = 0; i < 8; ++i) p4[i * 256 + t] = zz;
  }
  {  // stage Q,K: lane L -> row (t>>3), 16B-chunk (L&7)^(L>>3)  (swizzled slot L)
    const int kcs = ((lane & 7) ^ (lane >> 3)) * 8;
    const ushort* qg = qkv + (size_t)(b * 2048 + l0 + (t >> 3)) * 3072 + hd * 64 + kcs;
    ushort* ql = Qs + wid * 512;
    ushort* kl = Ks + wid * 512;
#pragma unroll
    for (int h2 = 0; h2 < 4; ++h2) {
      glds16(qg + (size_t)h2 * 32 * 3072, ql + h2 * 2048);
      glds16(qg + (size_t)h2 * 32 * 3072 + 1024, kl + h2 * 2048);
    }
  }

  // prefix-state accumulation (independent of LDS; overlaps phase-1)
  float run[16];
#pragma unroll
  for (int j = 0; j < 16; ++j) run[j] = 0.f;
  {
    const float4* mb = (const float4*)mlocT + (size_t)bh * 16384 + (size_t)t * 4;
    for (int cp = 0; cp < c; ++cp) {
      const float4* mc = mb + (size_t)cp * 1024;
#pragma unroll
      for (int k = 0; k < 4; ++k) {
        const float4 m = mc[k];
        run[k * 4 + 0] += m.x; run[k * 4 + 1] += m.y;
        run[k * 4 + 2] += m.z; run[k * 4 + 3] += m.w;
      }
    }
  }
  __syncthreads();

  bf16x8 qf[2][2];
#pragma unroll
  for (int i = 0; i < 2; ++i)
#pragma unroll
    for (int kc = 0; kc < 2; ++kc)
      qf[i][kc] = *(const bf16x8*)(Qs + ((wid * 2 + i) * 16 + l16) * 64 +
                                   (((kc * 4 + quad) ^ (l16 & 7)) * 8));

  const f32x4 z4 = {0.f, 0.f, 0.f, 0.f};
  f32x4 pacc[2][8];
#pragma unroll
  for (int i = 0; i < 2; ++i)
#pragma unroll
    for (int j = 0; j < 8; ++j) pacc[i][j] = z4;

#pragma unroll
  for (int i = 0; i < 2; ++i) {
    const int rt = wid * 2 + i;
#pragma unroll
    for (int tj = 0; tj < 8; ++tj) {
      if (tj <= rt) {
#pragma unroll
        for (int kc = 0; kc < 2; ++kc) {
          bf16x8 kfr = *(const bf16x8*)(Ks + (tj * 16 + l16) * 64 +
                                        (((kc * 4 + quad) ^ (l16 & 7)) * 8));
          pacc[i][tj] = __builtin_amdgcn_mfma_f32_16x16x32_bf16(qf[i][kc], kfr, pacc[i][tj], 0, 0, 0);
        }
      }
    }
  }
  __syncthreads();

  // write masked P, XOR-swizzled by row&7 (scol 16B-chunk scol>>3 ^ row&7)
#pragma unroll
  for (int i = 0; i < 2; ++i) {
    const int rt = wid * 2 + i;
#pragma unroll
    for (int tj = 0; tj < 8; ++tj) {
      if (tj <= rt) {
#pragma unroll
        for (int r = 0; r < 4; ++r) {
          const int row = rt * 16 + quad * 4 + r;
          const int scol = tj * 16 + l16;
          const float v = (scol <= row) ? pacc[i][tj][r] : 0.f;
          P[row * 128 + (((scol >> 3) ^ (row & 7)) * 8) + (scol & 7)] = f2bf(v);
        }
      }
    }
  }
  {  // stage V transposed: vT[e][s], stride 136
    const int sstep = t >> 1, eb = (t & 1) * 32;
    const ushort* vg = qkv + (size_t)(b * 2048 + l0 + sstep) * 3072 + 2048 + hd * 64 + eb;
    ushort tmp[32];
    *(uint4*)(tmp + 0)  = *(const uint4*)(vg + 0);
    *(uint4*)(tmp + 8)  = *(const uint4*)(vg + 8);
    *(uint4*)(tmp + 16) = *(const uint4*)(vg + 16);
    *(uint4*)(tmp + 24) = *(const uint4*)(vg + 24);
#pragma unroll
    for (int j = 0; j < 32; ++j) vT[(eb + j) * 136 + sstep] = tmp[j];
  }
  {  // state -> sT [e][f] stride 72 (bf16)
#pragma unroll
    for (int j = 0; j < 16; ++j) {
      const int ef = t * 16 + j;
      sT[(ef >> 6) * 72 + (ef & 63)] = f2bf(run[j]);
    }
  }
  __syncthreads();

  f32x4 yacc[2][4];
#pragma unroll
  for (int i = 0; i < 2; ++i)
#pragma unroll
    for (int j = 0; j < 4; ++j) yacc[i][j] = z4;

#pragma unroll
  for (int i = 0; i < 2; ++i) {
    const int rt = wid * 2 + i;
    const int kcmax = rt >> 1;
#pragma unroll
    for (int kc = 0; kc < 4; ++kc) {
      if (kc <= kcmax) {
        // P fragment: row rt*16+l16, k-chunks kc*32.. (two 16B chunks, swizzled)
        const int prow = rt * 16 + l16;
        bf16x8 pf;
        *(uint4*)&pf = *(const uint4*)(P + prow * 128 + (((kc * 4 + quad) ^ (prow & 7)) * 8));
#pragma unroll
        for (int ct = 0; ct < 4; ++ct) {
          bf16x8 vf = *(const bf16x8*)(vT + (ct * 16 + l16) * 136 + kc * 32 + quad * 8);
          yacc[i][ct] = __builtin_amdgcn_mfma_f32_16x16x32_bf16(pf, vf, yacc[i][ct], 0, 0, 0);
        }
      }
    }
#pragma unroll
    for (int kc = 0; kc < 2; ++kc) {
#pragma unroll
      for (int ct = 0; ct < 4; ++ct) {
        bf16x8 sf = *(const bf16x8*)(sT + (ct * 16 + l16) * 72 + kc * 32 + quad * 8);
        yacc[i][ct] = __builtin_amdgcn_mfma_f32_16x16x32_bf16(qf[i][kc], sf, yacc[i][ct], 0, 0, 0);
      }
    }
  }

#pragma unroll
  for (int i = 0; i < 2; ++i) {
    const int rt = wid * 2 + i;
#pragma unroll
    for (int ct = 0; ct < 4; ++ct) {
#pragma unroll
      for (int r = 0; r < 4; ++r) {
        const int row = rt * 16 + quad * 4 + r;
        const int e = ct * 16 + l16;
        yb[(size_t)(b * 2048 + l0 + row) * 1024 + hd * 64 + e] = f2bf(yacc[i][ct][r]);
      }
    }
  }
}

extern "C" void kernel_launch(void* const* d_in, const int* in_sizes, int n_in,
                              void* d_out, int out_size, void* d_ws, size_t ws_size,
                              hipStream_t stream) {
  const float* x  = (const float*)d_in[0];
  const float* Ww = (const float*)d_in[1];
  const float* Wb = (const float*)d_in[2];
  const float* Ow = (const float*)d_in[3];
  const float* Ob = (const float*)d_in[4];
  float* out = (float*)d_out;

  char* ws = (char*)d_ws;
  ushort* xb    = (ushort*)(ws);
  ushort* wqkvb = (ushort*)(ws + (size_t)8  * 1024 * 1024);
  ushort* outwb = (ushort*)(ws + (size_t)14 * 1024 * 1024);
  ushort* qkvb  = (ushort*)(ws + (size_t)16 * 1024 * 1024);
  float*  mlocT = (float*) (ws + (size_t)40 * 1024 * 1024);
  ushort* yb    = (ushort*)(ws + (size_t)48 * 1024 * 1024);

  cvt_all<<<8192, 256, 0, stream>>>(x, Ww, Ow, xb, wqkvb, outwb);
  gemm_bt<true, true><<<dim3(24, 32), 256, 0, stream>>>(xb, wqkvb, Wb, (void*)qkvb, 4096, 3072, 1024);
  kv_local<<<dim3(16, 32), 256, 0, stream>>>(qkvb, mlocT);
  attn_chunk<<<dim3(16, 32), 256, 0, stream>>>(qkvb, mlocT, yb);
  gemm_out64<<<dim3(8, 64), 256, 0, stream>>>(yb, outwb, Ob, out, 4096, 1024, 1024);
}

// Round 4
// 170.406 us; speedup vs baseline: 1.2078x; 1.1154x over previous
//
#include <hip/hip_runtime.h>

// LinearAttention: B=2, L=2048, D=1024, H=16, d=64.
// cvt_all ; QKV GEMM ; kv_local (MFMA) ; attn_chunk (prefix folded) ; out GEMM.
// R3 lesson: global_load_lds lane-address order dominates LDS read conflicts
// (identity 43.4 w/ 3.1M conflicts < swizzled 46.0 w/ 0). GEMMs use identity
// round-1 staging. attn_chunk keeps its swizzle (fixes 16-way, not 8-way).

#define DEV __device__ __forceinline__

typedef __attribute__((ext_vector_type(8))) short bf16x8;
typedef __attribute__((ext_vector_type(4))) float f32x4;

DEV ushort f2bf(float f) {
  union { float f; unsigned u; } v; v.f = f;
  unsigned r = v.u + 0x7fffu + ((v.u >> 16) & 1u);
  return (ushort)(r >> 16);
}
DEV float bf2f(unsigned b) {
  union { unsigned u; float f; } v; v.u = (b & 0xffffu) << 16;
  return v.f;
}
DEV void glds16(const ushort* g, ushort* l) {
  __builtin_amdgcn_global_load_lds(
      (const __attribute__((address_space(1))) unsigned int*)g,
      (__attribute__((address_space(3))) unsigned int*)l, 16, 0, 0);
}

__global__ __launch_bounds__(256) void cvt_all(const float* __restrict__ x,
                                               const float* __restrict__ Ww,
                                               const float* __restrict__ Ow,
                                               ushort* __restrict__ xb,
                                               ushort* __restrict__ wqkvb,
                                               ushort* __restrict__ outwb) {
  int i = blockIdx.x * 256 + threadIdx.x;
  const float* src; ushort* dst; int off;
  if (i < 1048576)      { src = x;  dst = xb;    off = i; }
  else if (i < 1835008) { src = Ww; dst = wqkvb; off = i - 1048576; }
  else                  { src = Ow; dst = outwb; off = i - 1835008; }
  float4 v = ((const float4*)src)[off];
  ushort4 o;
  o.x = f2bf(v.x); o.y = f2bf(v.y); o.z = f2bf(v.z); o.w = f2bf(v.w);
  ((ushort4*)dst)[off] = o;
}

// C = A[M,K] * Bw[N,K]^T + bias ; 128x128x32 tiles, round-1 identity staging.
template <bool OUT_BF16, bool KSCALE>
__global__ __launch_bounds__(256) void gemm_bt(const ushort* __restrict__ A,
                                               const ushort* __restrict__ Bw,
                                               const float* __restrict__ bias,
                                               void* __restrict__ Cout,
                                               int M, int N, int K) {
  __shared__ ushort As[128 * 32];  // row-major [row][32]
  __shared__ ushort Bs[128 * 32];
  const int t = threadIdx.x;
  const int wid = t >> 6, lane = t & 63;
  const int quad = lane >> 4, l16 = lane & 15;
  const int bm = blockIdx.y * 128, bn = blockIdx.x * 128;
  const int wm = (wid >> 1) * 64, wn = (wid & 1) * 64;

  f32x4 acc[4][4];
  const f32x4 z = {0.f, 0.f, 0.f, 0.f};
#pragma unroll
  for (int i = 0; i < 4; ++i)
#pragma unroll
    for (int j = 0; j < 4; ++j) acc[i][j] = z;

  const ushort* ag = A + (size_t)(bm + (t >> 2)) * K + ((t & 3) * 8);
  const ushort* bg = Bw + (size_t)(bn + (t >> 2)) * K + ((t & 3) * 8);
  ushort* asl = As + wid * 512;
  ushort* bsl = Bs + wid * 512;
  const size_t rowskip = (size_t)64 * K;

  for (int k0 = 0; k0 < K; k0 += 32) {
    glds16(ag + k0, asl);
    glds16(ag + k0 + rowskip, asl + 2048);
    glds16(bg + k0, bsl);
    glds16(bg + k0 + rowskip, bsl + 2048);
    __syncthreads();
    bf16x8 af[4], bf[4];
#pragma unroll
    for (int i = 0; i < 4; ++i) {
      af[i] = *(const bf16x8*)(As + (wm + i * 16 + l16) * 32 + quad * 8);
      bf[i] = *(const bf16x8*)(Bs + (wn + i * 16 + l16) * 32 + quad * 8);
    }
#pragma unroll
    for (int i = 0; i < 4; ++i)
#pragma unroll
      for (int j = 0; j < 4; ++j)
        acc[i][j] = __builtin_amdgcn_mfma_f32_16x16x32_bf16(af[i], bf[j], acc[i][j], 0, 0, 0);
    __syncthreads();
  }

#pragma unroll
  for (int i = 0; i < 4; ++i)
#pragma unroll
    for (int j = 0; j < 4; ++j) {
      const int col = bn + wn + j * 16 + l16;
      const float bv = bias[col];
      float sc = 1.f;
      if (KSCALE) sc = ((col >> 10) == 1) ? 0.125f : 1.f;
#pragma unroll
      for (int r = 0; r < 4; ++r) {
        const int row = bm + wm + i * 16 + quad * 4 + r;
        const float v = (acc[i][j][r] + bv) * sc;
        if (OUT_BF16)
          ((ushort*)Cout)[(size_t)row * N + col] = f2bf(v);
        else
          ((float*)Cout)[(size_t)row * N + col] = v;
      }
    }
}

// Out projection: BM=64, BN=128 -> 512 blocks (2/CU), identity staging.
__global__ __launch_bounds__(256) void gemm_out64(const ushort* __restrict__ A,
                                                  const ushort* __restrict__ Bw,
                                                  const float* __restrict__ bias,
                                                  float* __restrict__ C,
                                                  int M, int N, int K) {
  __shared__ ushort As[64 * 32];
  __shared__ ushort Bs[128 * 32];
  const int t = threadIdx.x;
  const int wid = t >> 6, lane = t & 63;
  const int quad = lane >> 4, l16 = lane & 15;
  const int bm = blockIdx.y * 64, bn = blockIdx.x * 128;
  const int wn = wid * 32;

  f32x4 acc[4][2];
  const f32x4 z = {0.f, 0.f, 0.f, 0.f};
#pragma unroll
  for (int i = 0; i < 4; ++i) { acc[i][0] = z; acc[i][1] = z; }

  const ushort* ag = A + (size_t)(bm + (t >> 2)) * K + ((t & 3) * 8);
  const ushort* bg = Bw + (size_t)(bn + (t >> 2)) * K + ((t & 3) * 8);
  ushort* asl = As + wid * 512;
  ushort* bsl = Bs + wid * 512;
  const size_t rowskip = (size_t)64 * K;

  for (int k0 = 0; k0 < K; k0 += 32) {
    glds16(ag + k0, asl);
    glds16(bg + k0, bsl);
    glds16(bg + k0 + rowskip, bsl + 2048);
    __syncthreads();
    bf16x8 af[4], bf[2];
#pragma unroll
    for (int i = 0; i < 4; ++i)
      af[i] = *(const bf16x8*)(As + (i * 16 + l16) * 32 + quad * 8);
#pragma unroll
    for (int j = 0; j < 2; ++j)
      bf[j] = *(const bf16x8*)(Bs + (wn + j * 16 + l16) * 32 + quad * 8);
#pragma unroll
    for (int i = 0; i < 4; ++i)
#pragma unroll
      for (int j = 0; j < 2; ++j)
        acc[i][j] = __builtin_amdgcn_mfma_f32_16x16x32_bf16(af[i], bf[j], acc[i][j], 0, 0, 0);
    __syncthreads();
  }

#pragma unroll
  for (int i = 0; i < 4; ++i)
#pragma unroll
    for (int j = 0; j < 2; ++j) {
      const int col = bn + wn + j * 16 + l16;
      const float bv = bias[col];
#pragma unroll
      for (int r = 0; r < 4; ++r) {
        const int row = bm + i * 16 + quad * 4 + r;
        C[(size_t)row * N + col] = acc[i][j][r] + bv;
      }
    }
}

// Per-(bh,chunk) KV sums via MFMA: mlocT[bh][c][e][f] = sum_s v[s][e]*k[s][f].
// Stage kT[f][s], vT[e][s] (stride 136); 1 thread = 1 full 128B row ->
// coalesced loads, transpose writes hit 32 banks 2-way (free).
__global__ __launch_bounds__(256) void kv_local(const ushort* __restrict__ qkv,
                                                float* __restrict__ mlocT) {
  const int c = blockIdx.x, bh = blockIdx.y;
  const int b = bh >> 4, hd = bh & 15;
  const int t = threadIdx.x;
  const int wid = t >> 6, lane = t & 63;
  const int quad = lane >> 4, l16 = lane & 15;
  __shared__ ushort kT[64 * 136];  // [f:64][s:128] + pad 8
  __shared__ ushort vT[64 * 136];  // [e:64][s:128] + pad 8

  {
    const int row = t & 127;                 // s index
    const int isv = t >> 7;                  // 0: K, 1: V
    const ushort* g = qkv + (size_t)(b * 2048 + c * 128 + row) * 3072 +
                      1024 + isv * 1024 + hd * 64;
    ushort tmp[64];
#pragma unroll
    for (int q = 0; q < 8; ++q) *(uint4*)(tmp + q * 8) = *(const uint4*)(g + q * 8);
    ushort* dst = isv ? vT : kT;
#pragma unroll
    for (int j = 0; j < 64; ++j) dst[j * 136 + row] = tmp[j];
  }
  __syncthreads();

  // wave wid: e-strip [wid*16, wid*16+16) x all 64 f
  const f32x4 z = {0.f, 0.f, 0.f, 0.f};
  f32x4 acc[4];
#pragma unroll
  for (int ct = 0; ct < 4; ++ct) acc[ct] = z;
#pragma unroll
  for (int kc = 0; kc < 4; ++kc) {
    bf16x8 afr = *(const bf16x8*)(vT + (wid * 16 + l16) * 136 + kc * 32 + quad * 8);
#pragma unroll
    for (int ct = 0; ct < 4; ++ct) {
      bf16x8 bfr = *(const bf16x8*)(kT + (ct * 16 + l16) * 136 + kc * 32 + quad * 8);
      acc[ct] = __builtin_amdgcn_mfma_f32_16x16x32_bf16(afr, bfr, acc[ct], 0, 0, 0);
    }
  }

  float* outp = mlocT + ((size_t)bh * 16 + c) * 4096;
#pragma unroll
  for (int ct = 0; ct < 4; ++ct)
#pragma unroll
    for (int r = 0; r < 4; ++r)
      outp[(wid * 16 + quad * 4 + r) * 64 + ct * 16 + l16] = acc[ct][r];
}

// Per-(bh,chunk): P = tril(Q K^T) ; Y = P V + Q S_prefix (prefix from mlocT).
__global__ __launch_bounds__(256) void attn_chunk(const ushort* __restrict__ qkv,
                                                  const float* __restrict__ mlocT,
                                                  ushort* __restrict__ yb) {
  const int c = blockIdx.x, bh = blockIdx.y;
  const int b = bh >> 4, hd = bh & 15;
  const int l0 = c * 128;
  const int t = threadIdx.x;
  const int wid = t >> 6, lane = t & 63;
  const int quad = lane >> 4, l16 = lane & 15;

  __shared__ ushort P[16384];  // [row][16B chunks] XOR-swizzled by row&7
  __shared__ ushort U[16384];
  ushort* Qs = U;              // [row:128][64] chunk^(row&7) swizzle
  ushort* Ks = U + 8192;
  ushort* vT = U;              // phase2: [e:64][s:128] stride 136
  ushort* sT = U + 8704;       // phase2: [e:64][f:64]  stride 72

  {  // zero P
    uint4 zz; zz.x = zz.y = zz.z = zz.w = 0u;
    uint4* p4 = (uint4*)P;
#pragma unroll
    for (int i = 0; i < 8; ++i) p4[i * 256 + t] = zz;
  }
  {  // stage Q,K swizzled: lane L -> row t>>3, 16B-chunk (L&7)^(L>>3)
    const int kcs = ((lane & 7) ^ (lane >> 3)) * 8;
    const ushort* qg = qkv + (size_t)(b * 2048 + l0 + (t >> 3)) * 3072 + hd * 64 + kcs;
    ushort* ql = Qs + wid * 512;
    ushort* kl = Ks + wid * 512;
#pragma unroll
    for (int h2 = 0; h2 < 4; ++h2) {
      glds16(qg + (size_t)h2 * 32 * 3072, ql + h2 * 2048);
      glds16(qg + (size_t)h2 * 32 * 3072 + 1024, kl + h2 * 2048);
    }
  }

  // prefix-state accumulation (overlaps staging latency)
  float run[16];
#pragma unroll
  for (int j = 0; j < 16; ++j) run[j] = 0.f;
  {
    const float4* mb = (const float4*)mlocT + (size_t)bh * 16384 + (size_t)t * 4;
    for (int cp = 0; cp < c; ++cp) {
      const float4* mc = mb + (size_t)cp * 1024;
#pragma unroll
      for (int k = 0; k < 4; ++k) {
        const float4 m = mc[k];
        run[k * 4 + 0] += m.x; run[k * 4 + 1] += m.y;
        run[k * 4 + 2] += m.z; run[k * 4 + 3] += m.w;
      }
    }
  }
  __syncthreads();

  bf16x8 qf[2][2];
#pragma unroll
  for (int i = 0; i < 2; ++i)
#pragma unroll
    for (int kc = 0; kc < 2; ++kc)
      qf[i][kc] = *(const bf16x8*)(Qs + ((wid * 2 + i) * 16 + l16) * 64 +
                                   (((kc * 4 + quad) ^ (l16 & 7)) * 8));

  const f32x4 z4 = {0.f, 0.f, 0.f, 0.f};
  f32x4 pacc[2][8];
#pragma unroll
  for (int i = 0; i < 2; ++i)
#pragma unroll
    for (int j = 0; j < 8; ++j) pacc[i][j] = z4;

#pragma unroll
  for (int i = 0; i < 2; ++i) {
    const int rt = wid * 2 + i;
#pragma unroll
    for (int tj = 0; tj < 8; ++tj) {
      if (tj <= rt) {
#pragma unroll
        for (int kc = 0; kc < 2; ++kc) {
          bf16x8 kfr = *(const bf16x8*)(Ks + (tj * 16 + l16) * 64 +
                                        (((kc * 4 + quad) ^ (l16 & 7)) * 8));
          pacc[i][tj] = __builtin_amdgcn_mfma_f32_16x16x32_bf16(qf[i][kc], kfr, pacc[i][tj], 0, 0, 0);
        }
      }
    }
  }
  __syncthreads();

#pragma unroll
  for (int i = 0; i < 2; ++i) {
    const int rt = wid * 2 + i;
#pragma unroll
    for (int tj = 0; tj < 8; ++tj) {
      if (tj <= rt) {
#pragma unroll
        for (int r = 0; r < 4; ++r) {
          const int row = rt * 16 + quad * 4 + r;
          const int scol = tj * 16 + l16;
          const float v = (scol <= row) ? pacc[i][tj][r] : 0.f;
          P[row * 128 + (((scol >> 3) ^ (row & 7)) * 8) + (scol & 7)] = f2bf(v);
        }
      }
    }
  }
  {  // stage V transposed: vT[e][s], stride 136
    const int sstep = t >> 1, eb = (t & 1) * 32;
    const ushort* vg = qkv + (size_t)(b * 2048 + l0 + sstep) * 3072 + 2048 + hd * 64 + eb;
    ushort tmp[32];
    *(uint4*)(tmp + 0)  = *(const uint4*)(vg + 0);
    *(uint4*)(tmp + 8)  = *(const uint4*)(vg + 8);
    *(uint4*)(tmp + 16) = *(const uint4*)(vg + 16);
    *(uint4*)(tmp + 24) = *(const uint4*)(vg + 24);
#pragma unroll
    for (int j = 0; j < 32; ++j) vT[(eb + j) * 136 + sstep] = tmp[j];
  }
  {  // state -> sT [e][f] stride 72 (bf16)
#pragma unroll
    for (int j = 0; j < 16; ++j) {
      const int ef = t * 16 + j;
      sT[(ef >> 6) * 72 + (ef & 63)] = f2bf(run[j]);
    }
  }
  __syncthreads();

  f32x4 yacc[2][4];
#pragma unroll
  for (int i = 0; i < 2; ++i)
#pragma unroll
    for (int j = 0; j < 4; ++j) yacc[i][j] = z4;

#pragma unroll
  for (int i = 0; i < 2; ++i) {
    const int rt = wid * 2 + i;
    const int kcmax = rt >> 1;
#pragma unroll
    for (int kc = 0; kc < 4; ++kc) {
      if (kc <= kcmax) {
        const int prow = rt * 16 + l16;
        bf16x8 pf;
        *(uint4*)&pf = *(const uint4*)(P + prow * 128 + (((kc * 4 + quad) ^ (prow & 7)) * 8));
#pragma unroll
        for (int ct = 0; ct < 4; ++ct) {
          bf16x8 vf = *(const bf16x8*)(vT + (ct * 16 + l16) * 136 + kc * 32 + quad * 8);
          yacc[i][ct] = __builtin_amdgcn_mfma_f32_16x16x32_bf16(pf, vf, yacc[i][ct], 0, 0, 0);
        }
      }
    }
#pragma unroll
    for (int kc = 0; kc < 2; ++kc) {
#pragma unroll
      for (int ct = 0; ct < 4; ++ct) {
        bf16x8 sf = *(const bf16x8*)(sT + (ct * 16 + l16) * 72 + kc * 32 + quad * 8);
        yacc[i][ct] = __builtin_amdgcn_mfma_f32_16x16x32_bf16(qf[i][kc], sf, yacc[i][ct], 0, 0, 0);
      }
    }
  }

#pragma unroll
  for (int i = 0; i < 2; ++i) {
    const int rt = wid * 2 + i;
#pragma unroll
    for (int ct = 0; ct < 4; ++ct) {
#pragma unroll
      for (int r = 0; r < 4; ++r) {
        const int row = rt * 16 + quad * 4 + r;
        const int e = ct * 16 + l16;
        yb[(size_t)(b * 2048 + l0 + row) * 1024 + hd * 64 + e] = f2bf(yacc[i][ct][r]);
      }
    }
  }
}

extern "C" void kernel_launch(void* const* d_in, const int* in_sizes, int n_in,
                              void* d_out, int out_size, void* d_ws, size_t ws_size,
                              hipStream_t stream) {
  const float* x  = (const float*)d_in[0];
  const float* Ww = (const float*)d_in[1];
  const float* Wb = (const float*)d_in[2];
  const float* Ow = (const float*)d_in[3];
  const float* Ob = (const float*)d_in[4];
  float* out = (float*)d_out;

  char* ws = (char*)d_ws;
  ushort* xb    = (ushort*)(ws);
  ushort* wqkvb = (ushort*)(ws + (size_t)8  * 1024 * 1024);
  ushort* outwb = (ushort*)(ws + (size_t)14 * 1024 * 1024);
  ushort* qkvb  = (ushort*)(ws + (size_t)16 * 1024 * 1024);
  float*  mlocT = (float*) (ws + (size_t)40 * 1024 * 1024);
  ushort* yb    = (ushort*)(ws + (size_t)48 * 1024 * 1024);

  cvt_all<<<8192, 256, 0, stream>>>(x, Ww, Ow, xb, wqkvb, outwb);
  gemm_bt<true, true><<<dim3(24, 32), 256, 0, stream>>>(xb, wqkvb, Wb, (void*)qkvb, 4096, 3072, 1024);
  kv_local<<<dim3(16, 32), 256, 0, stream>>>(qkvb, mlocT);
  attn_chunk<<<dim3(16, 32), 256, 0, stream>>>(qkvb, mlocT, yb);
  gemm_out64<<<dim3(8, 64), 256, 0, stream>>>(yb, outwb, Ob, out, 4096, 1024, 1024);
}

// Round 5
// 164.711 us; speedup vs baseline: 1.2496x; 1.0346x over previous
//
#include <hip/hip_runtime.h>

// LinearAttention: B=2, L=2048, D=1024, H=16, d=64.
// cvt_all ; QKV GEMM (BK=64) ; kv_local (MFMA) ; kv_prefix ; attn_chunk ; out GEMM (BK=64).
// R2-R4 lessons: glds16 global addresses must keep 8-lane 128B-row runs
// (identity footprint); XOR col-swizzle WITHIN a run is free and buys 2-way
// LDS reads; 8-way read conflicts were hidden anyway; prefix-fold's O(C^2)
// mlocT re-read (245MB) replaced by separate 12MB kv_prefix pass.

#define DEV __device__ __forceinline__

typedef __attribute__((ext_vector_type(8))) short bf16x8;
typedef __attribute__((ext_vector_type(4))) float f32x4;

DEV ushort f2bf(float f) {
  union { float f; unsigned u; } v; v.f = f;
  unsigned r = v.u + 0x7fffu + ((v.u >> 16) & 1u);
  return (ushort)(r >> 16);
}
DEV float bf2f(unsigned b) {
  union { unsigned u; float f; } v; v.u = (b & 0xffffu) << 16;
  return v.f;
}
DEV void glds16(const ushort* g, ushort* l) {
  __builtin_amdgcn_global_load_lds(
      (const __attribute__((address_space(1))) unsigned int*)g,
      (__attribute__((address_space(3))) unsigned int*)l, 16, 0, 0);
}

__global__ __launch_bounds__(256) void cvt_all(const float* __restrict__ x,
                                               const float* __restrict__ Ww,
                                               const float* __restrict__ Ow,
                                               ushort* __restrict__ xb,
                                               ushort* __restrict__ wqkvb,
                                               ushort* __restrict__ outwb) {
  int i = blockIdx.x * 256 + threadIdx.x;
  const float* src; ushort* dst; int off;
  if (i < 1048576)      { src = x;  dst = xb;    off = i; }
  else if (i < 1835008) { src = Ww; dst = wqkvb; off = i - 1048576; }
  else                  { src = Ow; dst = outwb; off = i - 1835008; }
  float4 v = ((const float4*)src)[off];
  ushort4 o;
  o.x = f2bf(v.x); o.y = f2bf(v.y); o.z = f2bf(v.z); o.w = f2bf(v.w);
  ((ushort4*)dst)[off] = o;
}

// C = A[M,K]*Bw[N,K]^T + bias ; 128x128 tile, BK=64 (2 sub-steps per barrier).
// Staging: lane l fetches row (call*32 + wid*8 + l>>3), col8 (l&7)^(l>>3&7)
// -> LDS row-major [row][64] holds chunk col8^(row&7) at slot col8.
template <bool OUT_BF16, bool KSCALE>
__global__ __launch_bounds__(256) void gemm_bt(const ushort* __restrict__ A,
                                               const ushort* __restrict__ Bw,
                                               const float* __restrict__ bias,
                                               void* __restrict__ Cout,
                                               int M, int N, int K) {
  __shared__ ushort As[128 * 64];  // 16 KB
  __shared__ ushort Bs[128 * 64];  // 16 KB
  const int t = threadIdx.x;
  const int wid = t >> 6, lane = t & 63;
  const int quad = lane >> 4, l16 = lane & 15;
  const int l3 = lane >> 3, l7 = lane & 7;
  const int bm = blockIdx.y * 128, bn = blockIdx.x * 128;
  const int wm = (wid >> 1) * 64, wn = (wid & 1) * 64;

  f32x4 acc[4][4];
  const f32x4 z = {0.f, 0.f, 0.f, 0.f};
#pragma unroll
  for (int i = 0; i < 4; ++i)
#pragma unroll
    for (int j = 0; j < 4; ++j) acc[i][j] = z;

  const ushort* ag = A + (size_t)(bm + wid * 8 + l3) * K + ((l7 ^ (l3 & 7)) * 8);
  const ushort* bg = Bw + (size_t)(bn + wid * 8 + l3) * K + ((l7 ^ (l3 & 7)) * 8);
  ushort* asl = As + wid * 512;
  ushort* bsl = Bs + wid * 512;
  const size_t rs = (size_t)32 * K;  // 32 rows per staging call

  for (int k0 = 0; k0 < K; k0 += 64) {
#pragma unroll
    for (int i = 0; i < 4; ++i) {
      glds16(ag + k0 + (size_t)i * rs, asl + i * 2048);
      glds16(bg + k0 + (size_t)i * rs, bsl + i * 2048);
    }
    __syncthreads();
#pragma unroll
    for (int ks = 0; ks < 2; ++ks) {
      bf16x8 af[4], bf[4];
#pragma unroll
      for (int i = 0; i < 4; ++i) {
        const int sw = (((ks * 4 + quad) ^ (l16 & 7)) * 8);
        af[i] = *(const bf16x8*)(As + (wm + i * 16 + l16) * 64 + sw);
        bf[i] = *(const bf16x8*)(Bs + (wn + i * 16 + l16) * 64 + sw);
      }
#pragma unroll
      for (int i = 0; i < 4; ++i)
#pragma unroll
        for (int j = 0; j < 4; ++j)
          acc[i][j] = __builtin_amdgcn_mfma_f32_16x16x32_bf16(af[i], bf[j], acc[i][j], 0, 0, 0);
    }
    __syncthreads();
  }

#pragma unroll
  for (int i = 0; i < 4; ++i)
#pragma unroll
    for (int j = 0; j < 4; ++j) {
      const int col = bn + wn + j * 16 + l16;
      const float bv = bias[col];
      float sc = 1.f;
      if (KSCALE) sc = ((col >> 10) == 1) ? 0.125f : 1.f;
#pragma unroll
      for (int r = 0; r < 4; ++r) {
        const int row = bm + wm + i * 16 + quad * 4 + r;
        const float v = (acc[i][j][r] + bv) * sc;
        if (OUT_BF16)
          ((ushort*)Cout)[(size_t)row * N + col] = f2bf(v);
        else
          ((float*)Cout)[(size_t)row * N + col] = v;
      }
    }
}

// Out projection: BM=64, BN=128, BK=64 -> 512 blocks (2/CU).
__global__ __launch_bounds__(256) void gemm_out64(const ushort* __restrict__ A,
                                                  const ushort* __restrict__ Bw,
                                                  const float* __restrict__ bias,
                                                  float* __restrict__ C,
                                                  int M, int N, int K) {
  __shared__ ushort As[64 * 64];   // 8 KB
  __shared__ ushort Bs[128 * 64];  // 16 KB
  const int t = threadIdx.x;
  const int wid = t >> 6, lane = t & 63;
  const int quad = lane >> 4, l16 = lane & 15;
  const int l3 = lane >> 3, l7 = lane & 7;
  const int bm = blockIdx.y * 64, bn = blockIdx.x * 128;
  const int wn = wid * 32;

  f32x4 acc[4][2];
  const f32x4 z = {0.f, 0.f, 0.f, 0.f};
#pragma unroll
  for (int i = 0; i < 4; ++i) { acc[i][0] = z; acc[i][1] = z; }

  const ushort* ag = A + (size_t)(bm + wid * 8 + l3) * K + ((l7 ^ (l3 & 7)) * 8);
  const ushort* bg = Bw + (size_t)(bn + wid * 8 + l3) * K + ((l7 ^ (l3 & 7)) * 8);
  ushort* asl = As + wid * 512;
  ushort* bsl = Bs + wid * 512;
  const size_t rs = (size_t)32 * K;

  for (int k0 = 0; k0 < K; k0 += 64) {
#pragma unroll
    for (int i = 0; i < 2; ++i) glds16(ag + k0 + (size_t)i * rs, asl + i * 2048);
#pragma unroll
    for (int i = 0; i < 4; ++i) glds16(bg + k0 + (size_t)i * rs, bsl + i * 2048);
    __syncthreads();
#pragma unroll
    for (int ks = 0; ks < 2; ++ks) {
      const int sw = (((ks * 4 + quad) ^ (l16 & 7)) * 8);
      bf16x8 af[4], bf[2];
#pragma unroll
      for (int i = 0; i < 4; ++i)
        af[i] = *(const bf16x8*)(As + (i * 16 + l16) * 64 + sw);
#pragma unroll
      for (int j = 0; j < 2; ++j)
        bf[j] = *(const bf16x8*)(Bs + (wn + j * 16 + l16) * 64 + sw);
#pragma unroll
      for (int i = 0; i < 4; ++i)
#pragma unroll
        for (int j = 0; j < 2; ++j)
          acc[i][j] = __builtin_amdgcn_mfma_f32_16x16x32_bf16(af[i], bf[j], acc[i][j], 0, 0, 0);
    }
    __syncthreads();
  }

#pragma unroll
  for (int i = 0; i < 4; ++i)
#pragma unroll
    for (int j = 0; j < 2; ++j) {
      const int col = bn + wn + j * 16 + l16;
      const float bv = bias[col];
#pragma unroll
      for (int r = 0; r < 4; ++r) {
        const int row = bm + i * 16 + quad * 4 + r;
        C[(size_t)row * N + col] = acc[i][j][r] + bv;
      }
    }
}

// Per-(bh,chunk) KV sums via MFMA: mlocT[bh][c][e][f] = sum_s v[s][e]*k[s][f].
__global__ __launch_bounds__(256) void kv_local(const ushort* __restrict__ qkv,
                                                float* __restrict__ mlocT) {
  const int c = blockIdx.x, bh = blockIdx.y;
  const int b = bh >> 4, hd = bh & 15;
  const int t = threadIdx.x;
  const int wid = t >> 6, lane = t & 63;
  const int quad = lane >> 4, l16 = lane & 15;
  __shared__ ushort kT[64 * 136];  // [f:64][s:128] pad 8
  __shared__ ushort vT[64 * 136];  // [e:64][s:128] pad 8

  {
    const int row = t & 127;
    const int isv = t >> 7;
    const ushort* g = qkv + (size_t)(b * 2048 + c * 128 + row) * 3072 +
                      1024 + isv * 1024 + hd * 64;
    ushort tmp[64];
#pragma unroll
    for (int q = 0; q < 8; ++q) *(uint4*)(tmp + q * 8) = *(const uint4*)(g + q * 8);
    ushort* dst = isv ? vT : kT;
#pragma unroll
    for (int j = 0; j < 64; ++j) dst[j * 136 + row] = tmp[j];
  }
  __syncthreads();

  const f32x4 z = {0.f, 0.f, 0.f, 0.f};
  f32x4 acc[4];
#pragma unroll
  for (int ct = 0; ct < 4; ++ct) acc[ct] = z;
#pragma unroll
  for (int kc = 0; kc < 4; ++kc) {
    bf16x8 afr = *(const bf16x8*)(vT + (wid * 16 + l16) * 136 + kc * 32 + quad * 8);
#pragma unroll
    for (int ct = 0; ct < 4; ++ct) {
      bf16x8 bfr = *(const bf16x8*)(kT + (ct * 16 + l16) * 136 + kc * 32 + quad * 8);
      acc[ct] = __builtin_amdgcn_mfma_f32_16x16x32_bf16(afr, bfr, acc[ct], 0, 0, 0);
    }
  }

  float* outp = mlocT + ((size_t)bh * 16 + c) * 4096;
#pragma unroll
  for (int ct = 0; ct < 4; ++ct)
#pragma unroll
    for (int r = 0; r < 4; ++r)
      outp[(wid * 16 + quad * 4 + r) * 64 + ct * 16 + l16] = acc[ct][r];
}

// Exclusive prefix over chunks, parallel over 4096 (e,f) entries per bh.
__global__ __launch_bounds__(256) void kv_prefix(const float* __restrict__ mlocT,
                                                 ushort* __restrict__ statesT) {
  const int slice = blockIdx.x, bh = blockIdx.y;
  const int eidx = slice * 256 + threadIdx.x;
  float run = 0.f;
  for (int c = 0; c < 16; ++c) {
    const size_t idx = ((size_t)bh * 16 + c) * 4096 + eidx;
    statesT[idx] = f2bf(run);
    run += mlocT[idx];
  }
}

// Per-(bh,chunk): P = tril(Q K^T) ; Y = P V + Q S_prefix (state from statesT).
__global__ __launch_bounds__(256) void attn_chunk(const ushort* __restrict__ qkv,
                                                  const ushort* __restrict__ statesT,
                                                  ushort* __restrict__ yb) {
  const int c = blockIdx.x, bh = blockIdx.y;
  const int b = bh >> 4, hd = bh & 15;
  const int l0 = c * 128;
  const int t = threadIdx.x;
  const int wid = t >> 6, lane = t & 63;
  const int quad = lane >> 4, l16 = lane & 15;

  __shared__ ushort P[16384];  // [row][16B chunks] XOR-swizzled by row&7
  __shared__ ushort U[16384];
  ushort* Qs = U;              // [row:128][64] chunk^(row&7)
  ushort* Ks = U + 8192;
  ushort* vT = U;              // phase2: [e:64][s:128] stride 136
  ushort* sT = U + 8704;       // phase2: [e:64][f:64]  stride 72

  {  // zero P
    uint4 zz; zz.x = zz.y = zz.z = zz.w = 0u;
    uint4* p4 = (uint4*)P;
#pragma unroll
    for (int i = 0; i < 8; ++i) p4[i * 256 + t] = zz;
  }
  {  // stage Q,K swizzled
    const int kcs = ((lane & 7) ^ (lane >> 3)) * 8;
    const ushort* qg = qkv + (size_t)(b * 2048 + l0 + (t >> 3)) * 3072 + hd * 64 + kcs;
    ushort* ql = Qs + wid * 512;
    ushort* kl = Ks + wid * 512;
#pragma unroll
    for (int h2 = 0; h2 < 4; ++h2) {
      glds16(qg + (size_t)h2 * 32 * 3072, ql + h2 * 2048);
      glds16(qg + (size_t)h2 * 32 * 3072 + 1024, kl + h2 * 2048);
    }
  }
  __syncthreads();

  bf16x8 qf[2][2];
#pragma unroll
  for (int i = 0; i < 2; ++i)
#pragma unroll
    for (int kc = 0; kc < 2; ++kc)
      qf[i][kc] = *(const bf16x8*)(Qs + ((wid * 2 + i) * 16 + l16) * 64 +
                                   (((kc * 4 + quad) ^ (l16 & 7)) * 8));

  const f32x4 z4 = {0.f, 0.f, 0.f, 0.f};
  f32x4 pacc[2][8];
#pragma unroll
  for (int i = 0; i < 2; ++i)
#pragma unroll
    for (int j = 0; j < 8; ++j) pacc[i][j] = z4;

#pragma unroll
  for (int i = 0; i < 2; ++i) {
    const int rt = wid * 2 + i;
#pragma unroll
    for (int tj = 0; tj < 8; ++tj) {
      if (tj <= rt) {
#pragma unroll
        for (int kc = 0; kc < 2; ++kc) {
          bf16x8 kfr = *(const bf16x8*)(Ks + (tj * 16 + l16) * 64 +
                                        (((kc * 4 + quad) ^ (l16 & 7)) * 8));
          pacc[i][tj] = __builtin_amdgcn_mfma_f32_16x16x32_bf16(qf[i][kc], kfr, pacc[i][tj], 0, 0, 0);
        }
      }
    }
  }
  __syncthreads();

#pragma unroll
  for (int i = 0; i < 2; ++i) {
    const int rt = wid * 2 + i;
#pragma unroll
    for (int tj = 0; tj < 8; ++tj) {
      if (tj <= rt) {
#pragma unroll
        for (int r = 0; r < 4; ++r) {
          const int row = rt * 16 + quad * 4 + r;
          const int scol = tj * 16 + l16;
          const float v = (scol <= row) ? pacc[i][tj][r] : 0.f;
          P[row * 128 + (((scol >> 3) ^ (row & 7)) * 8) + (scol & 7)] = f2bf(v);
        }
      }
    }
  }
  {  // stage V transposed: vT[e][s], stride 136
    const int sstep = t >> 1, eb = (t & 1) * 32;
    const ushort* vg = qkv + (size_t)(b * 2048 + l0 + sstep) * 3072 + 2048 + hd * 64 + eb;
    ushort tmp[32];
    *(uint4*)(tmp + 0)  = *(const uint4*)(vg + 0);
    *(uint4*)(tmp + 8)  = *(const uint4*)(vg + 8);
    *(uint4*)(tmp + 16) = *(const uint4*)(vg + 16);
    *(uint4*)(tmp + 24) = *(const uint4*)(vg + 24);
#pragma unroll
    for (int j = 0; j < 32; ++j) vT[(eb + j) * 136 + sstep] = tmp[j];
  }
  {  // stage state: 2 coalesced uint4 per thread -> sT stride 72
    const ushort* sg = statesT + ((size_t)bh * 16 + c) * 4096;
#pragma unroll
    for (int h = 0; h < 2; ++h) {
      const int cc = h * 256 + t;                 // 16B-chunk id 0..511
      uint4 d = *(const uint4*)(sg + cc * 8);
      *(uint4*)(sT + (cc >> 3) * 72 + (cc & 7) * 8) = d;
    }
  }
  __syncthreads();

  f32x4 yacc[2][4];
#pragma unroll
  for (int i = 0; i < 2; ++i)
#pragma unroll
    for (int j = 0; j < 4; ++j) yacc[i][j] = z4;

#pragma unroll
  for (int i = 0; i < 2; ++i) {
    const int rt = wid * 2 + i;
    const int kcmax = rt >> 1;
#pragma unroll
    for (int kc = 0; kc < 4; ++kc) {
      if (kc <= kcmax) {
        const int prow = rt * 16 + l16;
        bf16x8 pf;
        *(uint4*)&pf = *(const uint4*)(P + prow * 128 + (((kc * 4 + quad) ^ (prow & 7)) * 8));
#pragma unroll
        for (int ct = 0; ct < 4; ++ct) {
          bf16x8 vf = *(const bf16x8*)(vT + (ct * 16 + l16) * 136 + kc * 32 + quad * 8);
          yacc[i][ct] = __builtin_amdgcn_mfma_f32_16x16x32_bf16(pf, vf, yacc[i][ct], 0, 0, 0);
        }
      }
    }
#pragma unroll
    for (int kc = 0; kc < 2; ++kc) {
#pragma unroll
      for (int ct = 0; ct < 4; ++ct) {
        bf16x8 sf = *(const bf16x8*)(sT + (ct * 16 + l16) * 72 + kc * 32 + quad * 8);
        yacc[i][ct] = __builtin_amdgcn_mfma_f32_16x16x32_bf16(qf[i][kc], sf, yacc[i][ct], 0, 0, 0);
      }
    }
  }

#pragma unroll
  for (int i = 0; i < 2; ++i) {
    const int rt = wid * 2 + i;
#pragma unroll
    for (int ct = 0; ct < 4; ++ct) {
#pragma unroll
      for (int r = 0; r < 4; ++r) {
        const int row = rt * 16 + quad * 4 + r;
        const int e = ct * 16 + l16;
        yb[(size_t)(b * 2048 + l0 + row) * 1024 + hd * 64 + e] = f2bf(yacc[i][ct][r]);
      }
    }
  }
}

extern "C" void kernel_launch(void* const* d_in, const int* in_sizes, int n_in,
                              void* d_out, int out_size, void* d_ws, size_t ws_size,
                              hipStream_t stream) {
  const float* x  = (const float*)d_in[0];
  const float* Ww = (const float*)d_in[1];
  const float* Wb = (const float*)d_in[2];
  const float* Ow = (const float*)d_in[3];
  const float* Ob = (const float*)d_in[4];
  float* out = (float*)d_out;

  char* ws = (char*)d_ws;
  ushort* xb      = (ushort*)(ws);
  ushort* wqkvb   = (ushort*)(ws + (size_t)8  * 1024 * 1024);
  ushort* outwb   = (ushort*)(ws + (size_t)14 * 1024 * 1024);
  ushort* qkvb    = (ushort*)(ws + (size_t)16 * 1024 * 1024);
  float*  mlocT   = (float*) (ws + (size_t)40 * 1024 * 1024);
  ushort* statesT = (ushort*)(ws + (size_t)48 * 1024 * 1024);
  ushort* yb      = (ushort*)(ws + (size_t)52 * 1024 * 1024);

  cvt_all<<<8192, 256, 0, stream>>>(x, Ww, Ow, xb, wqkvb, outwb);
  gemm_bt<true, true><<<dim3(24, 32), 256, 0, stream>>>(xb, wqkvb, Wb, (void*)qkvb, 4096, 3072, 1024);
  kv_local<<<dim3(16, 32), 256, 0, stream>>>(qkvb, mlocT);
  kv_prefix<<<dim3(16, 32), 256, 0, stream>>>(mlocT, statesT);
  attn_chunk<<<dim3(16, 32), 256, 0, stream>>>(qkvb, statesT, yb);
  gemm_out64<<<dim3(8, 64), 256, 0, stream>>>(yb, outwb, Ob, out, 4096, 1024, 1024);
}

// Round 6
// 161.664 us; speedup vs baseline: 1.2731x; 1.0188x over previous
//
#include <hip/hip_runtime.h>

// LinearAttention: B=2, L=2048, D=1024, H=16, d=64.
// cvt_all ; QKV GEMM (BK=32) ; kv_local (MFMA) ; kv_prefix ; attn_chunk ; out GEMM (BK=32).
// R5 lesson: BK=64 regressed (32KB LDS halves resident blocks -> less implicit
// wave overlap; +11% FETCH). BK=32 identity staging is the proven optimum:
// 8-way LDS read conflicts are fully hidden under MFMA+staging (R3/R4 A/B).

#define DEV __device__ __forceinline__

typedef __attribute__((ext_vector_type(8))) short bf16x8;
typedef __attribute__((ext_vector_type(4))) float f32x4;

DEV ushort f2bf(float f) {
  union { float f; unsigned u; } v; v.f = f;
  unsigned r = v.u + 0x7fffu + ((v.u >> 16) & 1u);
  return (ushort)(r >> 16);
}
DEV float bf2f(unsigned b) {
  union { unsigned u; float f; } v; v.u = (b & 0xffffu) << 16;
  return v.f;
}
DEV void glds16(const ushort* g, ushort* l) {
  __builtin_amdgcn_global_load_lds(
      (const __attribute__((address_space(1))) unsigned int*)g,
      (__attribute__((address_space(3))) unsigned int*)l, 16, 0, 0);
}

__global__ __launch_bounds__(256) void cvt_all(const float* __restrict__ x,
                                               const float* __restrict__ Ww,
                                               const float* __restrict__ Ow,
                                               ushort* __restrict__ xb,
                                               ushort* __restrict__ wqkvb,
                                               ushort* __restrict__ outwb) {
  int i = blockIdx.x * 256 + threadIdx.x;
  const float* src; ushort* dst; int off;
  if (i < 1048576)      { src = x;  dst = xb;    off = i; }
  else if (i < 1835008) { src = Ww; dst = wqkvb; off = i - 1048576; }
  else                  { src = Ow; dst = outwb; off = i - 1835008; }
  float4 v = ((const float4*)src)[off];
  ushort4 o;
  o.x = f2bf(v.x); o.y = f2bf(v.y); o.z = f2bf(v.z); o.w = f2bf(v.w);
  ((ushort4*)dst)[off] = o;
}

// C = A[M,K]*Bw[N,K]^T + bias ; 128x128x32 tiles, round-1/4 identity staging.
template <bool OUT_BF16, bool KSCALE>
__global__ __launch_bounds__(256) void gemm_bt(const ushort* __restrict__ A,
                                               const ushort* __restrict__ Bw,
                                               const float* __restrict__ bias,
                                               void* __restrict__ Cout,
                                               int M, int N, int K) {
  __shared__ ushort As[128 * 32];
  __shared__ ushort Bs[128 * 32];
  const int t = threadIdx.x;
  const int wid = t >> 6, lane = t & 63;
  const int quad = lane >> 4, l16 = lane & 15;
  const int bm = blockIdx.y * 128, bn = blockIdx.x * 128;
  const int wm = (wid >> 1) * 64, wn = (wid & 1) * 64;

  f32x4 acc[4][4];
  const f32x4 z = {0.f, 0.f, 0.f, 0.f};
#pragma unroll
  for (int i = 0; i < 4; ++i)
#pragma unroll
    for (int j = 0; j < 4; ++j) acc[i][j] = z;

  const ushort* ag = A + (size_t)(bm + (t >> 2)) * K + ((t & 3) * 8);
  const ushort* bg = Bw + (size_t)(bn + (t >> 2)) * K + ((t & 3) * 8);
  ushort* asl = As + wid * 512;
  ushort* bsl = Bs + wid * 512;
  const size_t rowskip = (size_t)64 * K;

  for (int k0 = 0; k0 < K; k0 += 32) {
    glds16(ag + k0, asl);
    glds16(ag + k0 + rowskip, asl + 2048);
    glds16(bg + k0, bsl);
    glds16(bg + k0 + rowskip, bsl + 2048);
    __syncthreads();
    bf16x8 af[4], bf[4];
#pragma unroll
    for (int i = 0; i < 4; ++i) {
      af[i] = *(const bf16x8*)(As + (wm + i * 16 + l16) * 32 + quad * 8);
      bf[i] = *(const bf16x8*)(Bs + (wn + i * 16 + l16) * 32 + quad * 8);
    }
#pragma unroll
    for (int i = 0; i < 4; ++i)
#pragma unroll
      for (int j = 0; j < 4; ++j)
        acc[i][j] = __builtin_amdgcn_mfma_f32_16x16x32_bf16(af[i], bf[j], acc[i][j], 0, 0, 0);
    __syncthreads();
  }

#pragma unroll
  for (int i = 0; i < 4; ++i)
#pragma unroll
    for (int j = 0; j < 4; ++j) {
      const int col = bn + wn + j * 16 + l16;
      const float bv = bias[col];
      float sc = 1.f;
      if (KSCALE) sc = ((col >> 10) == 1) ? 0.125f : 1.f;
#pragma unroll
      for (int r = 0; r < 4; ++r) {
        const int row = bm + wm + i * 16 + quad * 4 + r;
        const float v = (acc[i][j][r] + bv) * sc;
        if (OUT_BF16)
          ((ushort*)Cout)[(size_t)row * N + col] = f2bf(v);
        else
          ((float*)Cout)[(size_t)row * N + col] = v;
      }
    }
}

// Out projection: BM=64, BN=128, BK=32 -> 512 blocks (2/CU), identity staging.
__global__ __launch_bounds__(256) void gemm_out64(const ushort* __restrict__ A,
                                                  const ushort* __restrict__ Bw,
                                                  const float* __restrict__ bias,
                                                  float* __restrict__ C,
                                                  int M, int N, int K) {
  __shared__ ushort As[64 * 32];
  __shared__ ushort Bs[128 * 32];
  const int t = threadIdx.x;
  const int wid = t >> 6, lane = t & 63;
  const int quad = lane >> 4, l16 = lane & 15;
  const int bm = blockIdx.y * 64, bn = blockIdx.x * 128;
  const int wn = wid * 32;

  f32x4 acc[4][2];
  const f32x4 z = {0.f, 0.f, 0.f, 0.f};
#pragma unroll
  for (int i = 0; i < 4; ++i) { acc[i][0] = z; acc[i][1] = z; }

  const ushort* ag = A + (size_t)(bm + (t >> 2)) * K + ((t & 3) * 8);
  const ushort* bg = Bw + (size_t)(bn + (t >> 2)) * K + ((t & 3) * 8);
  ushort* asl = As + wid * 512;
  ushort* bsl = Bs + wid * 512;
  const size_t rowskip = (size_t)64 * K;

  for (int k0 = 0; k0 < K; k0 += 32) {
    glds16(ag + k0, asl);
    glds16(bg + k0, bsl);
    glds16(bg + k0 + rowskip, bsl + 2048);
    __syncthreads();
    bf16x8 af[4], bf[2];
#pragma unroll
    for (int i = 0; i < 4; ++i)
      af[i] = *(const bf16x8*)(As + (i * 16 + l16) * 32 + quad * 8);
#pragma unroll
    for (int j = 0; j < 2; ++j)
      bf[j] = *(const bf16x8*)(Bs + (wn + j * 16 + l16) * 32 + quad * 8);
#pragma unroll
    for (int i = 0; i < 4; ++i)
#pragma unroll
      for (int j = 0; j < 2; ++j)
        acc[i][j] = __builtin_amdgcn_mfma_f32_16x16x32_bf16(af[i], bf[j], acc[i][j], 0, 0, 0);
    __syncthreads();
  }

#pragma unroll
  for (int i = 0; i < 4; ++i)
#pragma unroll
    for (int j = 0; j < 2; ++j) {
      const int col = bn + wn + j * 16 + l16;
      const float bv = bias[col];
#pragma unroll
      for (int r = 0; r < 4; ++r) {
        const int row = bm + i * 16 + quad * 4 + r;
        C[(size_t)row * N + col] = acc[i][j][r] + bv;
      }
    }
}

// Per-(bh,chunk) KV sums via MFMA: mlocT[bh][c][e][f] = sum_s v[s][e]*k[s][f].
__global__ __launch_bounds__(256) void kv_local(const ushort* __restrict__ qkv,
                                                float* __restrict__ mlocT) {
  const int c = blockIdx.x, bh = blockIdx.y;
  const int b = bh >> 4, hd = bh & 15;
  const int t = threadIdx.x;
  const int wid = t >> 6, lane = t & 63;
  const int quad = lane >> 4, l16 = lane & 15;
  __shared__ ushort kT[64 * 136];  // [f:64][s:128] pad 8
  __shared__ ushort vT[64 * 136];  // [e:64][s:128] pad 8

  {
    const int row = t & 127;
    const int isv = t >> 7;
    const ushort* g = qkv + (size_t)(b * 2048 + c * 128 + row) * 3072 +
                      1024 + isv * 1024 + hd * 64;
    ushort tmp[64];
#pragma unroll
    for (int q = 0; q < 8; ++q) *(uint4*)(tmp + q * 8) = *(const uint4*)(g + q * 8);
    ushort* dst = isv ? vT : kT;
#pragma unroll
    for (int j = 0; j < 64; ++j) dst[j * 136 + row] = tmp[j];
  }
  __syncthreads();

  const f32x4 z = {0.f, 0.f, 0.f, 0.f};
  f32x4 acc[4];
#pragma unroll
  for (int ct = 0; ct < 4; ++ct) acc[ct] = z;
#pragma unroll
  for (int kc = 0; kc < 4; ++kc) {
    bf16x8 afr = *(const bf16x8*)(vT + (wid * 16 + l16) * 136 + kc * 32 + quad * 8);
#pragma unroll
    for (int ct = 0; ct < 4; ++ct) {
      bf16x8 bfr = *(const bf16x8*)(kT + (ct * 16 + l16) * 136 + kc * 32 + quad * 8);
      acc[ct] = __builtin_amdgcn_mfma_f32_16x16x32_bf16(afr, bfr, acc[ct], 0, 0, 0);
    }
  }

  float* outp = mlocT + ((size_t)bh * 16 + c) * 4096;
#pragma unroll
  for (int ct = 0; ct < 4; ++ct)
#pragma unroll
    for (int r = 0; r < 4; ++r)
      outp[(wid * 16 + quad * 4 + r) * 64 + ct * 16 + l16] = acc[ct][r];
}

// Exclusive prefix over chunks, parallel over 4096 (e,f) entries per bh.
__global__ __launch_bounds__(256) void kv_prefix(const float* __restrict__ mlocT,
                                                 ushort* __restrict__ statesT) {
  const int slice = blockIdx.x, bh = blockIdx.y;
  const int eidx = slice * 256 + threadIdx.x;
  float run = 0.f;
  for (int c = 0; c < 16; ++c) {
    const size_t idx = ((size_t)bh * 16 + c) * 4096 + eidx;
    statesT[idx] = f2bf(run);
    run += mlocT[idx];
  }
}

// Per-(bh,chunk): P = tril(Q K^T) ; Y = P V + Q S_prefix (state from statesT).
__global__ __launch_bounds__(256) void attn_chunk(const ushort* __restrict__ qkv,
                                                  const ushort* __restrict__ statesT,
                                                  ushort* __restrict__ yb) {
  const int c = blockIdx.x, bh = blockIdx.y;
  const int b = bh >> 4, hd = bh & 15;
  const int l0 = c * 128;
  const int t = threadIdx.x;
  const int wid = t >> 6, lane = t & 63;
  const int quad = lane >> 4, l16 = lane & 15;

  __shared__ ushort P[16384];  // [row][16B chunks] XOR-swizzled by row&7
  __shared__ ushort U[16384];
  ushort* Qs = U;              // [row:128][64] chunk^(row&7)
  ushort* Ks = U + 8192;
  ushort* vT = U;              // phase2: [e:64][s:128] stride 136
  ushort* sT = U + 8704;       // phase2: [e:64][f:64]  stride 72

  {  // zero P
    uint4 zz; zz.x = zz.y = zz.z = zz.w = 0u;
    uint4* p4 = (uint4*)P;
#pragma unroll
    for (int i = 0; i < 8; ++i) p4[i * 256 + t] = zz;
  }
  {  // stage Q,K swizzled
    const int kcs = ((lane & 7) ^ (lane >> 3)) * 8;
    const ushort* qg = qkv + (size_t)(b * 2048 + l0 + (t >> 3)) * 3072 + hd * 64 + kcs;
    ushort* ql = Qs + wid * 512;
    ushort* kl = Ks + wid * 512;
#pragma unroll
    for (int h2 = 0; h2 < 4; ++h2) {
      glds16(qg + (size_t)h2 * 32 * 3072, ql + h2 * 2048);
      glds16(qg + (size_t)h2 * 32 * 3072 + 1024, kl + h2 * 2048);
    }
  }
  __syncthreads();

  bf16x8 qf[2][2];
#pragma unroll
  for (int i = 0; i < 2; ++i)
#pragma unroll
    for (int kc = 0; kc < 2; ++kc)
      qf[i][kc] = *(const bf16x8*)(Qs + ((wid * 2 + i) * 16 + l16) * 64 +
                                   (((kc * 4 + quad) ^ (l16 & 7)) * 8));

  const f32x4 z4 = {0.f, 0.f, 0.f, 0.f};
  f32x4 pacc[2][8];
#pragma unroll
  for (int i = 0; i < 2; ++i)
#pragma unroll
    for (int j = 0; j < 8; ++j) pacc[i][j] = z4;

#pragma unroll
  for (int i = 0; i < 2; ++i) {
    const int rt = wid * 2 + i;
#pragma unroll
    for (int tj = 0; tj < 8; ++tj) {
      if (tj <= rt) {
#pragma unroll
        for (int kc = 0; kc < 2; ++kc) {
          bf16x8 kfr = *(const bf16x8*)(Ks + (tj * 16 + l16) * 64 +
                                        (((kc * 4 + quad) ^ (l16 & 7)) * 8));
          pacc[i][tj] = __builtin_amdgcn_mfma_f32_16x16x32_bf16(qf[i][kc], kfr, pacc[i][tj], 0, 0, 0);
        }
      }
    }
  }
  __syncthreads();

#pragma unroll
  for (int i = 0; i < 2; ++i) {
    const int rt = wid * 2 + i;
#pragma unroll
    for (int tj = 0; tj < 8; ++tj) {
      if (tj <= rt) {
#pragma unroll
        for (int r = 0; r < 4; ++r) {
          const int row = rt * 16 + quad * 4 + r;
          const int scol = tj * 16 + l16;
          const float v = (scol <= row) ? pacc[i][tj][r] : 0.f;
          P[row * 128 + (((scol >> 3) ^ (row & 7)) * 8) + (scol & 7)] = f2bf(v);
        }
      }
    }
  }
  {  // stage V transposed: vT[e][s], stride 136
    const int sstep = t >> 1, eb = (t & 1) * 32;
    const ushort* vg = qkv + (size_t)(b * 2048 + l0 + sstep) * 3072 + 2048 + hd * 64 + eb;
    ushort tmp[32];
    *(uint4*)(tmp + 0)  = *(const uint4*)(vg + 0);
    *(uint4*)(tmp + 8)  = *(const uint4*)(vg + 8);
    *(uint4*)(tmp + 16) = *(const uint4*)(vg + 16);
    *(uint4*)(tmp + 24) = *(const uint4*)(vg + 24);
#pragma unroll
    for (int j = 0; j < 32; ++j) vT[(eb + j) * 136 + sstep] = tmp[j];
  }
  {  // stage state: 2 coalesced uint4 per thread -> sT stride 72
    const ushort* sg = statesT + ((size_t)bh * 16 + c) * 4096;
#pragma unroll
    for (int h = 0; h < 2; ++h) {
      const int cc = h * 256 + t;
      uint4 d = *(const uint4*)(sg + cc * 8);
      *(uint4*)(sT + (cc >> 3) * 72 + (cc & 7) * 8) = d;
    }
  }
  __syncthreads();

  f32x4 yacc[2][4];
#pragma unroll
  for (int i = 0; i < 2; ++i)
#pragma unroll
    for (int j = 0; j < 4; ++j) yacc[i][j] = z4;

#pragma unroll
  for (int i = 0; i < 2; ++i) {
    const int rt = wid * 2 + i;
    const int kcmax = rt >> 1;
#pragma unroll
    for (int kc = 0; kc < 4; ++kc) {
      if (kc <= kcmax) {
        const int prow = rt * 16 + l16;
        bf16x8 pf;
        *(uint4*)&pf = *(const uint4*)(P + prow * 128 + (((kc * 4 + quad) ^ (prow & 7)) * 8));
#pragma unroll
        for (int ct = 0; ct < 4; ++ct) {
          bf16x8 vf = *(const bf16x8*)(vT + (ct * 16 + l16) * 136 + kc * 32 + quad * 8);
          yacc[i][ct] = __builtin_amdgcn_mfma_f32_16x16x32_bf16(pf, vf, yacc[i][ct], 0, 0, 0);
        }
      }
    }
#pragma unroll
    for (int kc = 0; kc < 2; ++kc) {
#pragma unroll
      for (int ct = 0; ct < 4; ++ct) {
        bf16x8 sf = *(const bf16x8*)(sT + (ct * 16 + l16) * 72 + kc * 32 + quad * 8);
        yacc[i][ct] = __builtin_amdgcn_mfma_f32_16x16x32_bf16(qf[i][kc], sf, yacc[i][ct], 0, 0, 0);
      }
    }
  }

#pragma unroll
  for (int i = 0; i < 2; ++i) {
    const int rt = wid * 2 + i;
#pragma unroll
    for (int ct = 0; ct < 4; ++ct) {
#pragma unroll
      for (int r = 0; r < 4; ++r) {
        const int row = rt * 16 + quad * 4 + r;
        const int e = ct * 16 + l16;
        yb[(size_t)(b * 2048 + l0 + row) * 1024 + hd * 64 + e] = f2bf(yacc[i][ct][r]);
      }
    }
  }
}

extern "C" void kernel_launch(void* const* d_in, const int* in_sizes, int n_in,
                              void* d_out, int out_size, void* d_ws, size_t ws_size,
                              hipStream_t stream) {
  const float* x  = (const float*)d_in[0];
  const float* Ww = (const float*)d_in[1];
  const float* Wb = (const float*)d_in[2];
  const float* Ow = (const float*)d_in[3];
  const float* Ob = (const float*)d_in[4];
  float* out = (float*)d_out;

  char* ws = (char*)d_ws;
  ushort* xb      = (ushort*)(ws);
  ushort* wqkvb   = (ushort*)(ws + (size_t)8  * 1024 * 1024);
  ushort* outwb   = (ushort*)(ws + (size_t)14 * 1024 * 1024);
  ushort* qkvb    = (ushort*)(ws + (size_t)16 * 1024 * 1024);
  float*  mlocT   = (float*) (ws + (size_t)40 * 1024 * 1024);
  ushort* statesT = (ushort*)(ws + (size_t)48 * 1024 * 1024);
  ushort* yb      = (ushort*)(ws + (size_t)52 * 1024 * 1024);

  cvt_all<<<8192, 256, 0, stream>>>(x, Ww, Ow, xb, wqkvb, outwb);
  gemm_bt<true, true><<<dim3(24, 32), 256, 0, stream>>>(xb, wqkvb, Wb, (void*)qkvb, 4096, 3072, 1024);
  kv_local<<<dim3(16, 32), 256, 0, stream>>>(qkvb, mlocT);
  kv_prefix<<<dim3(16, 32), 256, 0, stream>>>(mlocT, statesT);
  attn_chunk<<<dim3(16, 32), 256, 0, stream>>>(qkvb, statesT, yb);
  gemm_out64<<<dim3(8, 64), 256, 0, stream>>>(yb, outwb, Ob, out, 4096, 1024, 1024);
}